// Round 6
// baseline (143.602 us; speedup 1.0000x reference)
//
#include <hip/hip_runtime.h>
#include <hip/hip_bf16.h>
#include <stdint.h>

#define B_ 2
#define N_ 4096
#define C_ 8
#define MAXDET 100
#define SCORE_THR 0.01f
#define NMS_THR 0.5f
#define NEGV -1e30f
#define CH 3               // chunks (x64 rows) covered by the precomputed mask

// ---------- helpers ----------
__device__ __forceinline__ unsigned mono_key(float f) {
    unsigned u = __float_as_uint(f);
    return (u & 0x80000000u) ? ~u : (u | 0x80000000u);
}
__device__ __forceinline__ float mono_dec(unsigned m) {
    return (m & 0x80000000u) ? __uint_as_float(m ^ 0x80000000u)
                             : __uint_as_float(~m);
}
// exact predicate: RN32(inter/uni) > 0.5  (uni > 0)
// <=> (exact) 2*inter > uni*(1+2^-25)  <=> (inter+inter-uni) > uni*2^-25
__device__ __forceinline__ bool iou_gt_half(float inter, float uni) {
    return (inter + inter - uni) > uni * 0x1p-25f;
}

// ---------- 1a) sort phase A: per-1024-chunk bitonic (64 blocks) ----------
__global__ __launch_bounds__(512) void sortA_kernel(
    const float* __restrict__ cls,
    unsigned long long* __restrict__ keys)   // (B*C, N)
{
    __shared__ unsigned long long k[1024];
    const int q = blockIdx.x;        // quarter 0..3
    const int bc = blockIdx.y;
    const int b = bc >> 3, c = bc & 7;
    const int tid = threadIdx.x;
    const bool desc = ((q & 1) == 0);

    for (int li = tid; li < 1024; li += 512) {
        int i = q * 1024 + li;
        float s = cls[((size_t)b * N_ + i) * C_ + c];
        float f = (s > SCORE_THR) ? s : NEGV;
        k[li] = ((unsigned long long)mono_key(f) << 32) | (unsigned)(~i);
    }
    __syncthreads();

    for (int size = 2; size <= 1024; size <<= 1) {
        for (int stride = size >> 1; stride > 0; stride >>= 1) {
            int t = tid;
            int pos = 2 * t - (t & (stride - 1));
            int par = pos + stride;
            bool d = ((pos & size) == 0) ? desc : !desc;
            unsigned long long a = k[pos], bb = k[par];
            if ((a < bb) == d) { k[pos] = bb; k[par] = a; }
            __syncthreads();
        }
    }

    for (int li = tid; li < 1024; li += 512)
        keys[(size_t)bc * N_ + q * 1024 + li] = k[li];
}

// ---------- 1b) sort phases B+C fused: merge 2048 then 4096, emit ----------
__global__ __launch_bounds__(1024) void sortBC_kernel(
    const unsigned long long* __restrict__ keys,
    const float* __restrict__ boxes,
    int* __restrict__ order,
    float* __restrict__ sscores,
    float4* __restrict__ sboxes)
{
    __shared__ unsigned long long k[4096];
    const int bc = blockIdx.x;
    const int b = bc >> 3;
    const int tid = threadIdx.x;
    const size_t base = (size_t)bc * N_;

    for (int i = tid; i < 4096; i += 1024) k[i] = keys[base + i];
    __syncthreads();

    for (int size = 2048; size <= 4096; size <<= 1) {
        for (int stride = size >> 1; stride > 0; stride >>= 1) {
            for (int t = tid; t < 2048; t += 1024) {
                int pos = 2 * t - (t & (stride - 1));
                int par = pos + stride;
                bool d = ((pos & size) == 0);       // size=4096: always desc
                unsigned long long a = k[pos], bb = k[par];
                if ((a < bb) == d) { k[pos] = bb; k[par] = a; }
            }
            __syncthreads();
        }
    }

    for (int p = tid; p < 4096; p += 1024) {
        unsigned long long kk = k[p];
        int orig = (int)(~(unsigned)kk);
        order[base + p] = orig;
        sscores[base + p] = mono_dec((unsigned)(kk >> 32));
        sboxes[base + p] = ((const float4*)boxes)[(size_t)b * N_ + orig];
    }
}

// ---------- 2) suppression bitmask, rows 0..CH*64-1 only ----------
// mask[(bc*CH*64 + i)*64 + w] bit t set iff j=w*64+t, j>i, IoU(i,j)>thr.
__global__ __launch_bounds__(256) void mask_lo_kernel(
    const float4* __restrict__ sboxes,
    unsigned long long* __restrict__ mask)
{
    __shared__ float4 sb[256];
    __shared__ float  sa[256];
    const int wg = blockIdx.x;
    const int chunk = blockIdx.y;
    const int bc = blockIdx.z;
    const int tid = threadIdx.x;
    const int lane = tid & 63;
    const int wave = tid >> 6;
    const size_t base = (size_t)bc * N_;
    const size_t mbase = (size_t)bc * (CH * 64);
    const int word = wg * 4 + wave;
    const int r = chunk * 64 + lane;

    float4 bs = sboxes[base + wg * 256 + tid];
    sb[tid] = bs;
    sa[tid] = (bs.z - bs.x) * (bs.w - bs.y);
    __syncthreads();

    unsigned long long bits = 0ull;
    if (word >= chunk) {
        float4 bi = sboxes[base + r];
        float aarea = (bi.z - bi.x) * (bi.w - bi.y);
        unsigned long long rm =
            (word > chunk) ? ~0ull : ~((2ull << lane) - 1ull);
        #pragma unroll 8
        for (int t = 0; t < 64; t++) {
            float4 bj = sb[wave * 64 + t];
            float barea = sa[wave * 64 + t];
            float ix1 = fmaxf(bi.x, bj.x);
            float iy1 = fmaxf(bi.y, bj.y);
            float ix2 = fminf(bi.z, bj.z);
            float iy2 = fminf(bi.w, bj.w);
            float inter = fmaxf(ix2 - ix1, 0.0f) * fmaxf(iy2 - iy1, 0.0f);
            float uni = fmaxf(aarea + barea - inter, 1e-9f);
            if (iou_gt_half(inter, uni)) bits |= (1ull << t);
        }
        bits &= rm;
    }
    mask[(mbase + r) * 64 + word] = bits;
}

// ---------- 3) greedy scan with inline fallback ----------
// One wave per (b,c). Lane w owns removal word w. Chunks < CH use the
// precomputed mask; chunks >= CH (rare/never) compute IoU on the fly.
__global__ __launch_bounds__(64) void scan_kernel(
    const unsigned long long* __restrict__ mask,
    const int* __restrict__ order,
    const float* __restrict__ sscores,
    const float4* __restrict__ sboxes,
    unsigned long long* __restrict__ cand)   // (B*C, 128) keys
{
    __shared__ unsigned long long shI[64];
    __shared__ float4 sbx[64];
    const int bc = blockIdx.x;
    const int lane = threadIdx.x;
    const size_t base = (size_t)bc * N_;
    const size_t mbase = (size_t)bc * (CH * 64);
    const int cls = bc & 7;

    cand[bc * 128 + lane] = 0ull;
    cand[bc * 128 + 64 + lane] = 0ull;

    unsigned long long remv = 0ull;
    int cand_count = 0;

    // ---- fast path: precomputed mask ----
    for (int c = 0; c < CH; c++) {
        const int p = c * 64 + lane;
        unsigned long long intra = mask[(mbase + p) * 64 + c];
        float sc = sscores[base + p];
        unsigned long long validb = __ballot(sc > -1e29f);
        if (validb == 0ull) return;          // sorted: tail all invalid

        __syncthreads();
        shI[lane] = intra;
        __syncthreads();

        unsigned long long curw = __shfl(remv, c, 64);
        unsigned long long kept = 0ull;
        #pragma unroll
        for (int t = 0; t < 64; t++) {
            unsigned long long bit = 1ull << t;
            if (!(curw & bit) && (validb & bit)) {
                kept |= bit;
                curw |= shI[t];
            }
        }

        if ((kept >> lane) & 1ull) {
            int rank = cand_count + __popcll(kept & ((1ull << lane) - 1ull));
            if (rank < 128) {
                int orig = order[base + p];
                unsigned flat = (unsigned)(cls * N_ + orig);
                cand[bc * 128 + rank] =
                    ((unsigned long long)mono_key(sc) << 32) | (unsigned)(~flat);
            }
        }
        cand_count += __popcll(kept);
        if (cand_count >= 128) return;

        unsigned long long acc = 0ull;
        #pragma unroll 8
        for (int t = 0; t < 64; t++) {
            unsigned long long rw = mask[(mbase + c * 64 + t) * 64 + lane];
            if ((kept >> t) & 1ull) acc |= rw;
        }
        remv |= acc;
    }

    // ---- slow path: on-the-fly IoU (executes only if 128 cand not reached) --
    for (int c = CH; c < 64; c++) {
        const int p = c * 64 + lane;
        float sc = sscores[base + p];
        unsigned long long validb = __ballot(sc > -1e29f);
        if (validb == 0ull) return;

        float4 bl = sboxes[base + p];
        __syncthreads();
        sbx[lane] = bl;
        __syncthreads();
        float al = (bl.z - bl.x) * (bl.w - bl.y);

        unsigned long long intra = 0ull;
        for (int t = lane + 1; t < 64; t++) {
            float4 bj = sbx[t];
            float ab = (bj.z - bj.x) * (bj.w - bj.y);
            float ix1 = fmaxf(bl.x, bj.x);
            float iy1 = fmaxf(bl.y, bj.y);
            float ix2 = fminf(bl.z, bj.z);
            float iy2 = fminf(bl.w, bj.w);
            float inter = fmaxf(ix2 - ix1, 0.0f) * fmaxf(iy2 - iy1, 0.0f);
            float uni = fmaxf(al + ab - inter, 1e-9f);
            if (iou_gt_half(inter, uni)) intra |= (1ull << t);
        }
        shI[lane] = intra;
        __syncthreads();

        unsigned long long curw = __shfl(remv, c, 64);
        unsigned long long kept = 0ull;
        #pragma unroll
        for (int t = 0; t < 64; t++) {
            unsigned long long bit = 1ull << t;
            if (!(curw & bit) && (validb & bit)) {
                kept |= bit;
                curw |= shI[t];
            }
        }

        if ((kept >> lane) & 1ull) {
            int rank = cand_count + __popcll(kept & ((1ull << lane) - 1ull));
            if (rank < 128) {
                int orig = order[base + p];
                unsigned flat = (unsigned)(cls * N_ + orig);
                cand[bc * 128 + rank] =
                    ((unsigned long long)mono_key(sc) << 32) | (unsigned)(~flat);
            }
        }
        cand_count += __popcll(kept);
        if (cand_count >= 128) return;

        // apply suppression of kept rows into future words (lane > c only)
        if (lane > c) {
            unsigned long long accw = 0ull;
            for (int tt = 0; tt < 64; tt++) {
                if (!((kept >> tt) & 1ull)) continue;
                float4 br = sbx[tt];
                float ar = (br.z - br.x) * (br.w - br.y);
                for (int u = 0; u < 64; u++) {
                    float4 bj = sboxes[base + lane * 64 + u];
                    float ab = (bj.z - bj.x) * (bj.w - bj.y);
                    float ix1 = fmaxf(br.x, bj.x);
                    float iy1 = fmaxf(br.y, bj.y);
                    float ix2 = fminf(br.z, bj.z);
                    float iy2 = fminf(br.w, bj.w);
                    float inter = fmaxf(ix2 - ix1, 0.0f) * fmaxf(iy2 - iy1, 0.0f);
                    float uni = fmaxf(ar + ab - inter, 1e-9f);
                    if (iou_gt_half(inter, uni)) accw |= (1ull << u);
                }
            }
            remv |= accw;
        }
    }
}

// ---------- 4) merge 8 sorted 128-lists -> top-100, write outputs ----------
__global__ __launch_bounds__(1024) void merge_kernel(
    const unsigned long long* __restrict__ cand,
    const float* __restrict__ boxes,
    const float* __restrict__ rot,
    const float* __restrict__ trans,
    float* __restrict__ out)
{
    __shared__ unsigned long long sk[1024];
    const int b = blockIdx.x;
    const int tid = threadIdx.x;
    const int c = tid >> 7, s = tid & 127;

    // per-class lists sorted desc; load odd classes reversed (asc)
    int src = (c & 1) ? (c * 128 + (127 - s)) : tid;
    sk[tid] = cand[(size_t)b * 1024 + src];

    // bitonic merge network only: 256 -> 512 -> 1024
    for (int size = 256; size <= 1024; size <<= 1) {
        for (int stride = size >> 1; stride > 0; stride >>= 1) {
            __syncthreads();
            int partner = tid ^ stride;
            if (partner > tid) {
                bool desc = ((tid & size) == 0);
                unsigned long long a = sk[tid], bb = sk[partner];
                if ((a < bb) == desc) { sk[tid] = bb; sk[partner] = a; }
            }
        }
    }
    __syncthreads();

    if (tid < MAXDET) {
        unsigned long long key = sk[tid];
        float score = mono_dec((unsigned)(key >> 32));
        bool ok = score > (NEGV * 0.5f);     // NaN padding -> false
        unsigned flat = (~(unsigned)key) & 32767u;
        int cc = flat >> 12;
        int n = flat & (N_ - 1);

        float* obox = out;                   // 800
        float* oscr = out + 800;             // 200
        float* olab = out + 1000;            // 200
        float* orot = out + 1200;            // 600
        float* otrn = out + 1800;            // 600

        #pragma unroll
        for (int d = 0; d < 4; d++)
            obox[b * 400 + tid * 4 + d] =
                ok ? boxes[((size_t)b * N_ + n) * 4 + d] : -1.0f;
        oscr[b * MAXDET + tid] = ok ? score : -1.0f;
        olab[b * MAXDET + tid] = ok ? (float)cc : -1.0f;
        #pragma unroll
        for (int d = 0; d < 3; d++) {
            orot[b * 300 + tid * 3 + d] =
                ok ? rot[((size_t)b * N_ + n) * 3 + d] : -1.0f;
            otrn[b * 300 + tid * 3 + d] =
                ok ? trans[((size_t)b * N_ + n) * 3 + d] : -1.0f;
        }
    }
}

extern "C" void kernel_launch(void* const* d_in, const int* in_sizes, int n_in,
                              void* d_out, int out_size, void* d_ws, size_t ws_size,
                              hipStream_t stream) {
    const float* boxes = (const float*)d_in[0];
    const float* cls   = (const float*)d_in[1];
    const float* rot   = (const float*)d_in[2];
    const float* trans = (const float*)d_in[3];
    float* out = (float*)d_out;

    char* w = (char*)d_ws;
    unsigned long long* mask = (unsigned long long*)w;
    w += (size_t)B_ * C_ * (CH * 64) * 64 * sizeof(unsigned long long); // 1.5 MB
    int* order = (int*)w;          w += (size_t)B_ * C_ * N_ * sizeof(int);
    float* sscores = (float*)w;    w += (size_t)B_ * C_ * N_ * sizeof(float);
    float4* sboxes = (float4*)w;   w += (size_t)B_ * C_ * N_ * sizeof(float4);
    unsigned long long* keys = (unsigned long long*)w;
    w += (size_t)B_ * C_ * N_ * sizeof(unsigned long long);
    unsigned long long* cand = (unsigned long long*)w;
    w += (size_t)B_ * C_ * 128 * sizeof(unsigned long long);

    sortA_kernel<<<dim3(4, B_ * C_), 512, 0, stream>>>(cls, keys);
    sortBC_kernel<<<B_ * C_, 1024, 0, stream>>>(keys, boxes, order, sscores, sboxes);
    mask_lo_kernel<<<dim3(16, CH, B_ * C_), 256, 0, stream>>>(sboxes, mask);
    scan_kernel<<<B_ * C_, 64, 0, stream>>>(mask, order, sscores, sboxes, cand);
    merge_kernel<<<B_, 1024, 0, stream>>>(cand, boxes, rot, trans, out);
}

// Round 7
// 99.578 us; speedup vs baseline: 1.4421x; 1.4421x over previous
//
#include <hip/hip_runtime.h>
#include <hip/hip_bf16.h>
#include <stdint.h>

#define B_ 2
#define N_ 4096
#define C_ 8
#define MAXDET 100
#define SCORE_THR 0.01f
#define NMS_THR 0.5f
#define NEGV -1e30f

typedef unsigned long long u64;

// ---------- helpers ----------
__device__ __forceinline__ unsigned mono_key(float f) {
    unsigned u = __float_as_uint(f);
    return (u & 0x80000000u) ? ~u : (u | 0x80000000u);
}
__device__ __forceinline__ float mono_dec(unsigned m) {
    return (m & 0x80000000u) ? __uint_as_float(m ^ 0x80000000u)
                             : __uint_as_float(~m);
}
// exact predicate: RN32(inter/uni) > 0.5  (uni > 0)
__device__ __forceinline__ bool iou_gt_half(float inter, float uni) {
    return (inter + inter - uni) > uni * 0x1p-25f;
}
// wave-synchronous LDS fence (single-wave producer/consumer, no s_barrier)
__device__ __forceinline__ void wave_fence() {
    asm volatile("s_waitcnt lgkmcnt(0)" ::: "memory");
}

// ---------- 1) sort phase A: per-1024-chunk bitonic, alternating dirs ------
__global__ __launch_bounds__(512) void sortA_kernel(
    const float* __restrict__ cls,
    u64* __restrict__ keys)   // (B*C, N)
{
    __shared__ u64 k[1024];
    const int q = blockIdx.x;        // quarter 0..3
    const int bc = blockIdx.y;
    const int b = bc >> 3, c = bc & 7;
    const int tid = threadIdx.x;
    const bool desc = ((q & 1) == 0);

    for (int li = tid; li < 1024; li += 512) {
        int i = q * 1024 + li;
        float s = cls[((size_t)b * N_ + i) * C_ + c];
        float f = (s > SCORE_THR) ? s : NEGV;
        k[li] = ((u64)mono_key(f) << 32) | (unsigned)(~i);
    }
    __syncthreads();

    for (int size = 2; size <= 1024; size <<= 1) {
        for (int stride = size >> 1; stride > 0; stride >>= 1) {
            int t = tid;
            int pos = 2 * t - (t & (stride - 1));
            int par = pos + stride;
            bool d = ((pos & size) == 0) ? desc : !desc;
            u64 a = k[pos], bb = k[par];
            if ((a < bb) == d) { k[pos] = bb; k[par] = a; }
            __syncthreads();
        }
    }

    for (int li = tid; li < 1024; li += 512)
        keys[(size_t)bc * N_ + q * 1024 + li] = k[li];
}

// ---------- 2) fused: top-1024 merge + mask + greedy scan (+gated fallback) -
__global__ __launch_bounds__(512) void fused_kernel(
    const u64* __restrict__ keys,
    const float* __restrict__ boxes,
    u64* __restrict__ cand)   // (B*C, 128)
{
    __shared__ u64 m[4096];          // fast: top-1024; fallback: all 4096
    __shared__ float4 sb192[192];
    __shared__ float  sa192[192];
    __shared__ u64 cm[576];          // 192 rows x 3 words
    __shared__ float4 sbx[64];       // fallback only
    __shared__ u64 shJ[64];          // fallback only
    __shared__ int s_fin;

    const int bc = blockIdx.x;
    const int b = bc >> 3, cls = bc & 7;
    const int tid = threadIdx.x;
    const int lane = tid & 63;
    const int wave = tid >> 6;
    const size_t kbase = (size_t)bc * N_;
    const float4* boxes4 = (const float4*)boxes;

    // ---- load 4 x top-256 (quarters sorted desc/asc/desc/asc by sortA) ----
    {
        int i = tid;
        int q = i >> 8;
        int off = q * 1024 + ((q & 1) ? 768 : 0) + (i & 255);
        m[i] = keys[kbase + off];
        i = tid + 512; q = i >> 8;
        off = q * 1024 + ((q & 1) ? 768 : 0) + (i & 255);
        m[i] = keys[kbase + off];
    }
    __syncthreads();

    // ---- finish bitonic network on m[0..1023] (stages size=512,1024) ----
    for (int size = 512; size <= 1024; size <<= 1) {
        for (int stride = size >> 1; stride > 0; stride >>= 1) {
            int pos = 2 * tid - (tid & (stride - 1));
            int par = pos + stride;
            bool d = ((pos & size) == 0);
            u64 a = m[pos], bb = m[par];
            if ((a < bb) == d) { m[pos] = bb; m[par] = a; }
            __syncthreads();
        }
    }

    // ---- gather top-192 boxes into LDS ----
    if (tid < 192) {
        int orig = (int)(~(unsigned)m[tid]);
        float4 bx = boxes4[(size_t)b * N_ + orig];
        sb192[tid] = bx;
        sa192[tid] = (bx.z - bx.x) * (bx.w - bx.y);
    }
    __syncthreads();

    // ---- cmask: 192 rows x 3 words, all in LDS ----
    for (int qq = tid; qq < 576; qq += 512) {
        int r = qq / 3, w = qq - 3 * r;
        int chunk = r >> 6;
        u64 bits = 0ull;
        if (w >= chunk) {
            float4 bi = sb192[r];
            float aarea = sa192[r];
            #pragma unroll 8
            for (int t = 0; t < 64; t++) {
                float4 bj = sb192[w * 64 + t];
                float barea = sa192[w * 64 + t];
                float ix1 = fmaxf(bi.x, bj.x);
                float iy1 = fmaxf(bi.y, bj.y);
                float ix2 = fminf(bi.z, bj.z);
                float iy2 = fminf(bi.w, bj.w);
                float inter = fmaxf(ix2 - ix1, 0.0f) * fmaxf(iy2 - iy1, 0.0f);
                float uni = fmaxf(aarea + barea - inter, 1e-9f);
                if (iou_gt_half(inter, uni)) bits |= (1ull << t);
            }
            if (w == chunk) bits &= ~((2ull << (r & 63)) - 1ull);
        }
        cm[qq] = bits;
    }
    __syncthreads();

    // ---- fast greedy scan, wave 0 only, fully LDS-resident ----
    if (wave == 0) {
        u64 remv = 0ull;     // lane w owns removal word w (only 0..2 used)
        int cc = 0;
        bool fin = false;
        for (int c = 0; c < 3; c++) {
            int p = c * 64 + lane;
            u64 key = m[p];
            float sc = mono_dec((unsigned)(key >> 32));
            u64 validb = __ballot(sc > -1e29f);
            if (validb == 0ull) { fin = true; break; }

            u64 curw = __shfl(remv, c, 64);
            u64 kept = 0ull;
            for (int t = 0; t < 64; t++) {
                u64 iv = cm[(c * 64 + t) * 3 + c];   // LDS broadcast
                u64 bit = 1ull << t;
                if (!(curw & bit) && (validb & bit)) { kept |= bit; curw |= iv; }
            }

            if ((kept >> lane) & 1ull) {
                int rank = cc + __popcll(kept & ((1ull << lane) - 1ull));
                if (rank < 128) {
                    int orig = (int)(~(unsigned)key);
                    unsigned flat = (unsigned)(cls * N_ + orig);
                    cand[bc * 128 + rank] =
                        ((u64)mono_key(sc) << 32) | (unsigned)(~flat);
                }
            }
            cc += __popcll(kept);
            if (cc >= 128) { fin = true; break; }

            if (lane < 3) {
                u64 acc = 0ull;
                for (int t = 0; t < 64; t++)
                    if ((kept >> t) & 1ull) acc |= cm[(c * 64 + t) * 3 + lane];
                remv |= acc;
            }
        }
        if (fin) {
            int filled = cc < 128 ? cc : 128;
            for (int s = lane; s < 128; s += 64)
                if (s >= filled) cand[bc * 128 + s] = 0ull;
        }
        if (lane == 0) s_fin = fin ? 1 : 0;
    }
    __syncthreads();
    if (s_fin) return;

    // ================= gated fallback (never on bench data) =================
    // finish the full 4096 sort in LDS, then wave-0 on-the-fly NMS.
    for (int i = tid; i < 4096; i += 512) m[i] = keys[kbase + i];
    __syncthreads();
    for (int size = 2048; size <= 4096; size <<= 1) {
        for (int stride = size >> 1; stride > 0; stride >>= 1) {
            for (int t = tid; t < 2048; t += 512) {
                int pos = 2 * t - (t & (stride - 1));
                int par = pos + stride;
                bool d = ((pos & size) == 0);
                u64 a = m[pos], bb = m[par];
                if ((a < bb) == d) { m[pos] = bb; m[par] = a; }
            }
            __syncthreads();
        }
    }
    if (wave != 0) return;

    {
        u64 remv = 0ull;
        int cc = 0;
        for (int c = 0; c < 64; c++) {
            int p = c * 64 + lane;
            u64 key = m[p];
            float sc = mono_dec((unsigned)(key >> 32));
            u64 validb = __ballot(sc > -1e29f);
            if (validb == 0ull) break;

            int orig = (int)(~(unsigned)key);
            float4 bl = boxes4[(size_t)b * N_ + orig];
            sbx[lane] = bl;
            wave_fence();
            float al = (bl.z - bl.x) * (bl.w - bl.y);

            u64 intra = 0ull;
            for (int t = 0; t < 64; t++) {
                float4 bj = sbx[t];
                float ab = (bj.z - bj.x) * (bj.w - bj.y);
                float ix1 = fmaxf(bl.x, bj.x);
                float iy1 = fmaxf(bl.y, bj.y);
                float ix2 = fminf(bl.z, bj.z);
                float iy2 = fminf(bl.w, bj.w);
                float inter = fmaxf(ix2 - ix1, 0.0f) * fmaxf(iy2 - iy1, 0.0f);
                float uni = fmaxf(al + ab - inter, 1e-9f);
                if (t > lane && iou_gt_half(inter, uni)) intra |= (1ull << t);
            }
            shJ[lane] = intra;
            wave_fence();

            u64 curw = __shfl(remv, c, 64);
            u64 kept = 0ull;
            for (int t = 0; t < 64; t++) {
                u64 iv = shJ[t];
                u64 bit = 1ull << t;
                if (!(curw & bit) && (validb & bit)) { kept |= bit; curw |= iv; }
            }

            if ((kept >> lane) & 1ull) {
                int rank = cc + __popcll(kept & ((1ull << lane) - 1ull));
                if (rank < 128) {
                    unsigned flat = (unsigned)(cls * N_ + orig);
                    cand[bc * 128 + rank] =
                        ((u64)mono_key(sc) << 32) | (unsigned)(~flat);
                }
            }
            cc += __popcll(kept);
            if (cc >= 128) break;

            if (lane > c) {
                u64 accw = 0ull;
                for (int u = 0; u < 64; u++) {
                    int pj = lane * 64 + u;
                    int oj = (int)(~(unsigned)m[pj]);
                    float4 bj = boxes4[(size_t)b * N_ + oj];
                    float ab = (bj.z - bj.x) * (bj.w - bj.y);
                    bool sup = false;
                    for (int tt = 0; tt < 64; tt++) {
                        if (!((kept >> tt) & 1ull)) continue;
                        float4 br = sbx[tt];
                        float ar = (br.z - br.x) * (br.w - br.y);
                        float ix1 = fmaxf(br.x, bj.x);
                        float iy1 = fmaxf(br.y, bj.y);
                        float ix2 = fminf(br.z, bj.z);
                        float iy2 = fminf(br.w, bj.w);
                        float inter = fmaxf(ix2 - ix1, 0.0f) * fmaxf(iy2 - iy1, 0.0f);
                        float uni = fmaxf(ar + ab - inter, 1e-9f);
                        if (iou_gt_half(inter, uni)) { sup = true; break; }
                    }
                    if (sup) accw |= (1ull << u);
                }
                remv |= accw;
            }
            wave_fence();
        }
        int filled = cc < 128 ? cc : 128;
        for (int s = lane; s < 128; s += 64)
            if (s >= filled) cand[bc * 128 + s] = 0ull;
    }
}

// ---------- 3) merge 8 sorted 128-lists -> top-100, write outputs ----------
__global__ __launch_bounds__(1024) void merge_kernel(
    const u64* __restrict__ cand,
    const float* __restrict__ boxes,
    const float* __restrict__ rot,
    const float* __restrict__ trans,
    float* __restrict__ out)
{
    __shared__ u64 sk[1024];
    const int b = blockIdx.x;
    const int tid = threadIdx.x;
    const int c = tid >> 7, s = tid & 127;

    // per-class lists sorted desc; load odd classes reversed (asc)
    int src = (c & 1) ? (c * 128 + (127 - s)) : tid;
    sk[tid] = cand[(size_t)b * 1024 + src];

    for (int size = 256; size <= 1024; size <<= 1) {
        for (int stride = size >> 1; stride > 0; stride >>= 1) {
            __syncthreads();
            int partner = tid ^ stride;
            if (partner > tid) {
                bool desc = ((tid & size) == 0);
                u64 a = sk[tid], bb = sk[partner];
                if ((a < bb) == desc) { sk[tid] = bb; sk[partner] = a; }
            }
        }
    }
    __syncthreads();

    if (tid < MAXDET) {
        u64 key = sk[tid];
        float score = mono_dec((unsigned)(key >> 32));
        bool ok = score > (NEGV * 0.5f);
        unsigned flat = (~(unsigned)key) & 32767u;
        int cc = flat >> 12;
        int n = flat & (N_ - 1);

        float* obox = out;                   // 800
        float* oscr = out + 800;             // 200
        float* olab = out + 1000;            // 200
        float* orot = out + 1200;            // 600
        float* otrn = out + 1800;            // 600

        #pragma unroll
        for (int d = 0; d < 4; d++)
            obox[b * 400 + tid * 4 + d] =
                ok ? boxes[((size_t)b * N_ + n) * 4 + d] : -1.0f;
        oscr[b * MAXDET + tid] = ok ? score : -1.0f;
        olab[b * MAXDET + tid] = ok ? (float)cc : -1.0f;
        #pragma unroll
        for (int d = 0; d < 3; d++) {
            orot[b * 300 + tid * 3 + d] =
                ok ? rot[((size_t)b * N_ + n) * 3 + d] : -1.0f;
            otrn[b * 300 + tid * 3 + d] =
                ok ? trans[((size_t)b * N_ + n) * 3 + d] : -1.0f;
        }
    }
}

extern "C" void kernel_launch(void* const* d_in, const int* in_sizes, int n_in,
                              void* d_out, int out_size, void* d_ws, size_t ws_size,
                              hipStream_t stream) {
    const float* boxes = (const float*)d_in[0];
    const float* cls   = (const float*)d_in[1];
    const float* rot   = (const float*)d_in[2];
    const float* trans = (const float*)d_in[3];
    float* out = (float*)d_out;

    char* w = (char*)d_ws;
    u64* keys = (u64*)w;   w += (size_t)B_ * C_ * N_ * sizeof(u64);   // 512 KB
    u64* cand = (u64*)w;   w += (size_t)B_ * C_ * 128 * sizeof(u64);  // 16 KB

    sortA_kernel<<<dim3(4, B_ * C_), 512, 0, stream>>>(cls, keys);
    fused_kernel<<<B_ * C_, 512, 0, stream>>>(keys, boxes, cand);
    merge_kernel<<<B_, 1024, 0, stream>>>(cand, boxes, rot, trans, out);
}